// Round 12
// baseline (534.334 us; speedup 1.0000x reference)
//
#include <hip/hip_runtime.h>
#include <hip/hip_bf16.h>

#define NIN  512
#define NHID 256
#define NOUT 64
#define HOPS 10

typedef __attribute__((ext_vector_type(8))) short bf16x8;
typedef __attribute__((ext_vector_type(4))) float f32x4;

__device__ __forceinline__ unsigned short f2bf(float f) {
    unsigned u = __float_as_uint(f);
    u += 0x7FFFu + ((u >> 16) & 1u);            // RNE
    return (unsigned short)(u >> 16);
}
__device__ __forceinline__ unsigned pk2(float a, float b) {
    return (unsigned)f2bf(a) | ((unsigned)f2bf(b) << 16);
}
__device__ __forceinline__ float bflo(unsigned g) { return __uint_as_float(g << 16); }
__device__ __forceinline__ float bfhi(unsigned g) { return __uint_as_float(g & 0xFFFF0000u); }

// ---------------------------------------------------------------------------
// Pre-permute W1, W2 into MFMA A-fragment order (bf16).  (verified R4/R5)
// ---------------------------------------------------------------------------
__global__ void k_preconv(const float* __restrict__ W1, const float* __restrict__ W2,
                          unsigned short* __restrict__ W1f, unsigned short* __restrict__ W2f)
{
    const int i = blockIdx.x * 256 + threadIdx.x;
    if (i < NHID * NIN) {
        const int j = i & 7, l = (i >> 3) & 63, fi = i >> 9;
        const int ks = fi >> 4, w = (fi >> 2) & 3, nf = fi & 3;
        const int col = w * 64 + nf * 16 + (l & 15);
        const int k   = ks * 32 + ((l >> 4) << 3) + j;
        W1f[i] = f2bf(W1[col * NIN + k]);
    }
    if (i < NOUT * NHID) {
        const int j = i & 7, l = (i >> 3) & 63, fi = i >> 9;
        const int ks = fi >> 2, nf = fi & 3;
        const int col = nf * 16 + (l & 15);
        const int k   = ks * 32 + ((j >> 2) << 4) + ((l >> 4) << 2) + (j & 3);
        W2f[i] = f2bf(W2[col * NHID + k]);
    }
}

// ---------------------------------------------------------------------------
// Fused MFMA MLP (operand-swapped, BK=32 — exact R10-verified version).
// ---------------------------------------------------------------------------
__global__ __launch_bounds__(256, 3) void mlp_kernel(
    const float* __restrict__ x, const unsigned short* __restrict__ W1f,
    const float* __restrict__ b1, const unsigned short* __restrict__ W2f,
    const float* __restrict__ b2,
    unsigned* __restrict__ hpack, int n)
{
    __shared__ __align__(16) char smem[50176];
    short* B2L  = (short*)smem;
    short* BX   = (short*)(smem + 32768);
    float* H0L  = (float*)(smem + 32768);

    const int t  = threadIdx.x;
    const int w  = t >> 6, lz = t & 63;
    const int row0 = blockIdx.x * 64;

    const int srow = t >> 2;
    int xrow = row0 + srow; if (xrow >= n) xrow = n - 1;
    const float4* xp = (const float4*)(x + (size_t)xrow * NIN);
    const int q4a = t & 3, q4b = (t & 3) + 4;

    f32x4 acc[4][4];
    #pragma unroll
    for (int a = 0; a < 4; ++a)
        #pragma unroll
        for (int b = 0; b < 4; ++b) acc[a][b] = (f32x4)(0.f);

    auto xwrite = [&](int b, float4 va, float4 vb) {
        unsigned long long pa = (unsigned long long)pk2(va.x, va.y)
                              | ((unsigned long long)pk2(va.z, va.w) << 32);
        unsigned long long pb = (unsigned long long)pk2(vb.x, vb.y)
                              | ((unsigned long long)pk2(vb.z, vb.w) << 32);
        *(unsigned long long*)&BX[(((((b << 2) + (srow >> 4)) << 6)
            + ((srow & 15) | ((q4a >> 1) << 4))) << 3) + ((q4a & 1) << 2)] = pa;
        *(unsigned long long*)&BX[(((((b << 2) + (srow >> 4)) << 6)
            + ((srow & 15) | ((q4b >> 1) << 4))) << 3) + ((q4b & 1) << 2)] = pb;
    };
    auto wload = [&](int kt, bf16x8* wf) {
        const unsigned short* wp = W1f + ((size_t)kt << 13) + (w << 11) + (lz << 3);
        #pragma unroll
        for (int hf = 0; hf < 4; ++hf)
            wf[hf] = *(const bf16x8*)(wp + (hf << 9));
    };
    auto compute = [&](int b, const bf16x8* wf) {
        bf16x8 xf[4];
        #pragma unroll
        for (int nfn = 0; nfn < 4; ++nfn)
            xf[nfn] = *(const bf16x8*)&BX[((((b << 2) + nfn) << 6) + lz) << 3];
        #pragma unroll
        for (int nfn = 0; nfn < 4; ++nfn)
            #pragma unroll
            for (int hf = 0; hf < 4; ++hf)
                acc[nfn][hf] = __builtin_amdgcn_mfma_f32_16x16x32_bf16(
                    wf[hf], xf[nfn], acc[nfn][hf], 0, 0, 0);
    };

    bf16x8 wfc[4], wfn[4];
    float4 sAa, sAb, sBa, sBb;
    {
        float4 xa = xp[q4a], xb = xp[q4b];
        wload(0, wfc);
        xwrite(0, xa, xb);
        sAa = xp[8 + q4a]; sAb = xp[8 + q4b];
    }
    __syncthreads();

    #pragma unroll 1
    for (int kt = 0; kt < 16; kt += 2) {
        if (kt + 2 < 16) { sBa = xp[((kt + 2) << 3) + q4a]; sBb = xp[((kt + 2) << 3) + q4b]; }
        wload(kt + 1, wfn);
        compute(0, wfc);
        xwrite(1, sAa, sAb);
        __syncthreads();
        if (kt + 3 < 16) { sAa = xp[((kt + 3) << 3) + q4a]; sAb = xp[((kt + 3) << 3) + q4b]; }
        if (kt + 2 < 16) wload(kt + 2, wfc);
        compute(1, wfn);
        if (kt + 2 < 16) xwrite(0, sBa, sBb);
        __syncthreads();
    }

    {
        float4 b1q[4];
        #pragma unroll
        for (int hf = 0; hf < 4; ++hf)
            b1q[hf] = *(const float4*)(b1 + (w << 6) + (hf << 4) + ((lz >> 4) << 2));
        #pragma unroll
        for (int nfn = 0; nfn < 4; ++nfn) {
            #pragma unroll
            for (int cl = 0; cl < 2; ++cl) {
                f32x4 a0 = acc[nfn][2 * cl], a1 = acc[nfn][2 * cl + 1];
                float4 c0 = b1q[2 * cl], c1 = b1q[2 * cl + 1];
                uint4 pv;
                pv.x = pk2(fmaxf(a0.x + c0.x, 0.f), fmaxf(a0.y + c0.y, 0.f));
                pv.y = pk2(fmaxf(a0.z + c0.z, 0.f), fmaxf(a0.w + c0.w, 0.f));
                pv.z = pk2(fmaxf(a1.x + c1.x, 0.f), fmaxf(a1.y + c1.y, 0.f));
                pv.w = pk2(fmaxf(a1.z + c1.z, 0.f), fmaxf(a1.w + c1.w, 0.f));
                *(uint4*)&B2L[((((nfn << 3) + (w << 1) + cl) << 6) + lz) << 3] = pv;
            }
        }
    }
    __syncthreads();

    f32x4 acc2[4];
    #pragma unroll
    for (int nf2 = 0; nf2 < 4; ++nf2) acc2[nf2] = (f32x4)(0.f);

    #pragma unroll
    for (int c = 0; c < 8; ++c) {
        bf16x8 hfrag = *(const bf16x8*)&B2L[((((w << 3) + c) << 6) + lz) << 3];
        #pragma unroll
        for (int nf2 = 0; nf2 < 4; ++nf2) {
            bf16x8 wfrag = *(const bf16x8*)(W2f + (((c << 2) + nf2) << 9) + (lz << 3));
            acc2[nf2] = __builtin_amdgcn_mfma_f32_16x16x32_bf16(
                wfrag, hfrag, acc2[nf2], 0, 0, 0);
        }
    }

    {
        const int mloc = (w << 4) + (lz & 15);
        #pragma unroll
        for (int nf2 = 0; nf2 < 4; ++nf2) {
            float4 bq = *(const float4*)(b2 + (nf2 << 4) + ((lz >> 4) << 2));
            float4 hv;
            hv.x = acc2[nf2].x + bq.x; hv.y = acc2[nf2].y + bq.y;
            hv.z = acc2[nf2].z + bq.z; hv.w = acc2[nf2].w + bq.w;
            *(float4*)&H0L[mloc * 68 + (nf2 << 4) + ((lz >> 4) << 2)] = hv;
        }
    }
    __syncthreads();

    {
        const int m = t >> 2, q = t & 3;
        const int g = row0 + m;
        if (g < n) {
            unsigned* hp = hpack + (size_t)g * 32 + (q << 3);
            #pragma unroll
            for (int i = 0; i < 16; i += 4) {
                float4 hv = *(const float4*)&H0L[m * 68 + (q << 4) + i];
                uint2 pv;
                pv.x = pk2(hv.x, hv.y);
                pv.y = pk2(hv.z, hv.w);
                *(uint2*)(hp + (i >> 1)) = pv;
            }
        }
    }
}

// ---------------------------------------------------------------------------
// CSR build via single-digit bucket sort (bucket = row >> 8).  (verified R9)
// Split arrays: brow (4B row ids) + bcv (8B col/val).  (kept from R11)
// ---------------------------------------------------------------------------
__global__ __launch_bounds__(256) void kA_hist(
    const int* __restrict__ erow, int* __restrict__ bcnt, int e, int nbk)
{
    __shared__ int lh[512];
    const int t = threadIdx.x;
    for (int b = t; b < 512; b += 256) lh[b] = 0;
    __syncthreads();
    for (int i = blockIdx.x * 256 + t; i < e; i += gridDim.x * 256)
        atomicAdd(&lh[erow[i] >> 8], 1);
    __syncthreads();
    for (int b = t; b < nbk; b += 256)
        if (lh[b]) atomicAdd(&bcnt[b], lh[b]);
}

__global__ __launch_bounds__(512) void kB_scan(
    const int* __restrict__ bcnt, int* __restrict__ bbase,
    int* __restrict__ gcur, int e, int nbk)
{
    __shared__ int sm[512];
    const int tid = threadIdx.x;
    const int v = (tid < nbk) ? bcnt[tid] : 0;
    sm[tid] = v;
    __syncthreads();
    for (int off = 1; off < 512; off <<= 1) {
        int tv = (tid >= off) ? sm[tid - off] : 0;
        __syncthreads();
        sm[tid] += tv;
        __syncthreads();
    }
    if (tid < nbk) {
        const int base = sm[tid] - v;
        bbase[tid] = base;
        gcur[tid * 16] = base;        // 64B-padded cursor
    }
    if (tid == 0) bbase[nbk] = e;
}

__global__ __launch_bounds__(256) void k_bapp(
    const int* __restrict__ erow, const int* __restrict__ ecol,
    const float* __restrict__ ev, int* __restrict__ gcur,
    unsigned* __restrict__ brow, uint2* __restrict__ bcv, int e, int nbk)
{
    __shared__ int lh[512];
    __shared__ int lbase[512];
    const int t = threadIdx.x;
    const int c0 = blockIdx.x * 4096;
    for (int b = t; b < 512; b += 256) lh[b] = 0;
    __syncthreads();
    int rr[16];
    #pragma unroll
    for (int j = 0; j < 16; ++j) {
        const int i = c0 + j * 256 + t;
        rr[j] = (i < e) ? erow[i] : -1;
        if (rr[j] >= 0) atomicAdd(&lh[rr[j] >> 8], 1);
    }
    __syncthreads();
    for (int b = t; b < nbk; b += 256) {
        const int c = lh[b];
        lbase[b] = c ? atomicAdd(&gcur[b * 16], c) : 0;
        lh[b] = 0;
    }
    __syncthreads();
    #pragma unroll
    for (int j = 0; j < 16; ++j) {
        const int i = c0 + j * 256 + t;
        if (rr[j] >= 0) {
            const int b  = rr[j] >> 8;
            const int rk = atomicAdd(&lh[b], 1);
            const int pos = lbase[b] + rk;
            brow[pos] = (unsigned)rr[j];
            uint2 cv; cv.x = (unsigned)ecol[i]; cv.y = __float_as_uint(ev[i]);
            bcv[pos] = cv;
        }
    }
}

__global__ __launch_bounds__(256) void k_brow(
    const unsigned* __restrict__ brow, const int* __restrict__ bbase,
    int* __restrict__ rp, int n, int e)
{
    __shared__ int rc[256];
    __shared__ int sc[256];
    const int b = blockIdx.x, t = threadIdx.x;
    const int lo = bbase[b], hi = bbase[b + 1];
    rc[t] = 0;
    __syncthreads();
    for (int i = lo + t; i < hi; i += 256)
        atomicAdd(&rc[brow[i] & 255], 1);
    __syncthreads();
    const int v = rc[t];
    sc[t] = v;
    __syncthreads();
    for (int off = 1; off < 256; off <<= 1) {
        int tv = (t >= off) ? sc[t - off] : 0;
        __syncthreads();
        sc[t] += tv;
        __syncthreads();
    }
    const int row = (b << 8) + t;
    if (row < n) rp[row] = lo + sc[t] - v;
    if (b == 0 && t == 0) rp[n] = e;
}

__global__ __launch_bounds__(256) void k_bwrite(
    const unsigned* __restrict__ brow, const uint2* __restrict__ bcv,
    const int* __restrict__ bbase, const int* __restrict__ rp,
    unsigned long long* __restrict__ cpack)
{
    __shared__ int rc[256];
    const int b = blockIdx.x, t = threadIdx.x;
    const int lo = bbase[b], hi = bbase[b + 1];
    rc[t] = 0;
    __syncthreads();
    for (int i = lo + t; i < hi; i += 256) {
        const unsigned r = brow[i];
        const uint2 cv = bcv[i];
        const int rk = atomicAdd(&rc[r & 255], 1);
        cpack[rp[r] + rk] = ((unsigned long long)cv.y << 32) | cv.x;
    }
}

// ---------------------------------------------------------------------------
// One propagation hop (pull, CSR, bf16-packed h). 8-deep gather pipeline.
// (verified R10)
// ---------------------------------------------------------------------------
__global__ __launch_bounds__(256) void hop_kernel(
    const unsigned* __restrict__ h_in, unsigned* __restrict__ h_out,
    const int* __restrict__ row_ptr, const unsigned long long* __restrict__ cpack,
    int n)
{
    const int t  = threadIdx.x;
    const int sl = t & 31;
    const int node = (blockIdx.x * 256 + t) >> 5;
    if (node >= n) return;
    const int start = row_ptr[node];
    const int end   = row_ptr[node + 1];
    float a0 = 0.f, a1 = 0.f;
    for (int base = start; base < end; base += 32) {
        const int idx = base + sl;
        unsigned long long pc = (idx < end) ? cpack[idx] : 0ULL;
        int   c = (int)(unsigned)pc;
        float v = __uint_as_float((unsigned)(pc >> 32));
        const int cnt = min(32, end - base);
        int e = 0;
        for (; e + 8 <= cnt; e += 8) {
            int cc[8]; float vv[8]; unsigned gg[8];
            #pragma unroll
            for (int j = 0; j < 8; ++j) {
                cc[j] = __shfl(c, e + j, 32);
                vv[j] = __shfl(v, e + j, 32);
            }
            #pragma unroll
            for (int j = 0; j < 8; ++j)
                gg[j] = h_in[(size_t)cc[j] * 32 + sl];
            #pragma unroll
            for (int j = 0; j < 8; ++j) {
                a0 = fmaf(vv[j], bflo(gg[j]), a0);
                a1 = fmaf(vv[j], bfhi(gg[j]), a1);
            }
        }
        for (; e + 4 <= cnt; e += 4) {
            int cc[4]; float vv[4]; unsigned gg[4];
            #pragma unroll
            for (int j = 0; j < 4; ++j) {
                cc[j] = __shfl(c, e + j, 32);
                vv[j] = __shfl(v, e + j, 32);
            }
            #pragma unroll
            for (int j = 0; j < 4; ++j)
                gg[j] = h_in[(size_t)cc[j] * 32 + sl];
            #pragma unroll
            for (int j = 0; j < 4; ++j) {
                a0 = fmaf(vv[j], bflo(gg[j]), a0);
                a1 = fmaf(vv[j], bfhi(gg[j]), a1);
            }
        }
        for (; e < cnt; ++e) {
            int   cc = __shfl(c, e, 32);
            float vv = __shfl(v, e, 32);
            unsigned g = h_in[(size_t)cc * 32 + sl];
            a0 = fmaf(vv, bflo(g), a0); a1 = fmaf(vv, bfhi(g), a1);
        }
    }
    h_out[(size_t)node * 32 + sl] = pk2(a0, a1);
}

// ---------------------------------------------------------------------------
// Final combine: sig_k(n) = sigmoid(h_k(n).s); out = sum_k sig_k(n) h_k(n)
// ---------------------------------------------------------------------------
__global__ __launch_bounds__(256) void k_combine(
    const unsigned* __restrict__ hbuf, const float* __restrict__ s,
    float* __restrict__ out, int n)
{
    const int gid  = blockIdx.x * 256 + threadIdx.x;
    const int node = gid >> 5, sl = gid & 31;
    if (node >= n) return;
    const float2 sv = ((const float2*)s)[sl];
    float o0 = 0.f, o1 = 0.f;
    #pragma unroll
    for (int k = 0; k <= HOPS; ++k) {
        const unsigned g = hbuf[(size_t)k * n * 32 + (size_t)node * 32 + sl];
        const float lo = bflo(g), hi = bfhi(g);
        float tv = lo * sv.x + hi * sv.y;
        #pragma unroll
        for (int off = 16; off > 0; off >>= 1) tv += __shfl_xor(tv, off, 32);
        const float sg = 1.f / (1.f + expf(-tv));
        o0 = fmaf(sg, lo, o0);
        o1 = fmaf(sg, hi, o1);
    }
    float2 ov; ov.x = o0; ov.y = o1;
    ((float2*)out)[(size_t)node * 32 + sl] = ov;
}

// ---------------------------------------------------------------------------
extern "C" void kernel_launch(void* const* d_in, const int* in_sizes, int n_in,
                              void* d_out, int out_size, void* d_ws, size_t ws_size,
                              hipStream_t stream)
{
    const float* x  = (const float*)d_in[0];
    const int*   er = (const int*)  d_in[1];
    const int*   ec = (const int*)  d_in[2];
    const float* ev = (const float*)d_in[3];
    const float* W1 = (const float*)d_in[4];
    const float* b1 = (const float*)d_in[5];
    const float* W2 = (const float*)d_in[6];
    const float* b2 = (const float*)d_in[7];
    const float* s  = (const float*)d_in[8];
    float* out = (float*)d_out;

    const int n = in_sizes[0] / NIN;   // 100000
    const int e = in_sizes[1];         // 1600000
    const int nbk = (n + 255) >> 8;    // 391 buckets

    char* w = (char*)d_ws;
    auto carve = [&](size_t bytes) { char* p = w; w += (bytes + 255) & ~(size_t)255; return p; };
    unsigned* hbuf   = (unsigned*)carve((size_t)(HOPS + 1) * n * 32 * 4);  // 140.8 MB
    int*      rp     = (int*)     carve(((size_t)n + 1) * 4);
    unsigned long long* cpack = (unsigned long long*)carve((size_t)e * 8); // 12.8 MB
    unsigned* brow   = (unsigned*)carve((size_t)e * 4);                    // 6.4 MB
    uint2*    bcv    = (uint2*)   carve((size_t)e * 8);                    // 12.8 MB
    int*      bcnt   = (int*)     carve(512 * 4);
    int*      bbase  = (int*)     carve(513 * 4);
    int*      gcur   = (int*)     carve(512 * 16 * 4);
    unsigned short* W1f = (unsigned short*)carve((size_t)NHID * NIN * 2);
    unsigned short* W2f = (unsigned short*)carve((size_t)NOUT * NHID * 2);

    hipMemsetAsync(bcnt, 0, 512 * 4, stream);

    k_preconv<<<(NHID * NIN + 255) / 256, 256, 0, stream>>>(W1, W2, W1f, W2f);

    const int mgrid = (n + 63) / 64;
    mlp_kernel<<<mgrid, 256, 0, stream>>>(x, W1f, b1, W2f, b2, hbuf, n);

    kA_hist <<<256, 256, 0, stream>>>(er, bcnt, e, nbk);
    kB_scan <<<1, 512, 0, stream>>>(bcnt, bbase, gcur, e, nbk);
    k_bapp  <<<(e + 4095) / 4096, 256, 0, stream>>>(er, ec, ev, gcur, brow, bcv, e, nbk);
    k_brow  <<<nbk, 256, 0, stream>>>(brow, bbase, rp, n, e);
    k_bwrite<<<nbk, 256, 0, stream>>>(brow, bcv, bbase, rp, cpack);

    const int hgrid = ((size_t)n * 32 + 255) / 256;
    for (int hop = 0; hop < HOPS; ++hop) {
        hop_kernel<<<hgrid, 256, 0, stream>>>(
            hbuf + (size_t)hop * n * 32, hbuf + (size_t)(hop + 1) * n * 32,
            rp, cpack, n);
    }

    k_combine<<<hgrid, 256, 0, stream>>>(hbuf, s, out, n);
}

// Round 13
// 503.352 us; speedup vs baseline: 1.0616x; 1.0616x over previous
//
#include <hip/hip_runtime.h>
#include <hip/hip_bf16.h>

#define NIN  512
#define NHID 256
#define NOUT 64
#define HOPS 10

typedef __attribute__((ext_vector_type(8))) short bf16x8;
typedef __attribute__((ext_vector_type(4))) float f32x4;

__device__ __forceinline__ unsigned short f2bf(float f) {
    unsigned u = __float_as_uint(f);
    u += 0x7FFFu + ((u >> 16) & 1u);            // RNE
    return (unsigned short)(u >> 16);
}
__device__ __forceinline__ unsigned pk2(float a, float b) {
    return (unsigned)f2bf(a) | ((unsigned)f2bf(b) << 16);
}
__device__ __forceinline__ float bflo(unsigned g) { return __uint_as_float(g << 16); }
__device__ __forceinline__ float bfhi(unsigned g) { return __uint_as_float(g & 0xFFFF0000u); }

// ---------------------------------------------------------------------------
// Pre-permute W1, W2 into MFMA A-fragment order (bf16).  (verified R4/R5)
// ---------------------------------------------------------------------------
__global__ void k_preconv(const float* __restrict__ W1, const float* __restrict__ W2,
                          unsigned short* __restrict__ W1f, unsigned short* __restrict__ W2f)
{
    const int i = blockIdx.x * 256 + threadIdx.x;
    if (i < NHID * NIN) {
        const int j = i & 7, l = (i >> 3) & 63, fi = i >> 9;
        const int ks = fi >> 4, w = (fi >> 2) & 3, nf = fi & 3;
        const int col = w * 64 + nf * 16 + (l & 15);
        const int k   = ks * 32 + ((l >> 4) << 3) + j;
        W1f[i] = f2bf(W1[col * NIN + k]);
    }
    if (i < NOUT * NHID) {
        const int j = i & 7, l = (i >> 3) & 63, fi = i >> 9;
        const int ks = fi >> 2, nf = fi & 3;
        const int col = nf * 16 + (l & 15);
        const int k   = ks * 32 + ((j >> 2) << 4) + ((l >> 4) << 2) + (j & 3);
        W2f[i] = f2bf(W2[col * NHID + k]);
    }
}

// ---------------------------------------------------------------------------
// Fused MFMA MLP (operand-swapped, BK=32 — exact R10-verified version).
// ---------------------------------------------------------------------------
__global__ __launch_bounds__(256, 3) void mlp_kernel(
    const float* __restrict__ x, const unsigned short* __restrict__ W1f,
    const float* __restrict__ b1, const unsigned short* __restrict__ W2f,
    const float* __restrict__ b2,
    unsigned* __restrict__ hpack, int n)
{
    __shared__ __align__(16) char smem[50176];
    short* B2L  = (short*)smem;
    short* BX   = (short*)(smem + 32768);
    float* H0L  = (float*)(smem + 32768);

    const int t  = threadIdx.x;
    const int w  = t >> 6, lz = t & 63;
    const int row0 = blockIdx.x * 64;

    const int srow = t >> 2;
    int xrow = row0 + srow; if (xrow >= n) xrow = n - 1;
    const float4* xp = (const float4*)(x + (size_t)xrow * NIN);
    const int q4a = t & 3, q4b = (t & 3) + 4;

    f32x4 acc[4][4];
    #pragma unroll
    for (int a = 0; a < 4; ++a)
        #pragma unroll
        for (int b = 0; b < 4; ++b) acc[a][b] = (f32x4)(0.f);

    auto xwrite = [&](int b, float4 va, float4 vb) {
        unsigned long long pa = (unsigned long long)pk2(va.x, va.y)
                              | ((unsigned long long)pk2(va.z, va.w) << 32);
        unsigned long long pb = (unsigned long long)pk2(vb.x, vb.y)
                              | ((unsigned long long)pk2(vb.z, vb.w) << 32);
        *(unsigned long long*)&BX[(((((b << 2) + (srow >> 4)) << 6)
            + ((srow & 15) | ((q4a >> 1) << 4))) << 3) + ((q4a & 1) << 2)] = pa;
        *(unsigned long long*)&BX[(((((b << 2) + (srow >> 4)) << 6)
            + ((srow & 15) | ((q4b >> 1) << 4))) << 3) + ((q4b & 1) << 2)] = pb;
    };
    auto wload = [&](int kt, bf16x8* wf) {
        const unsigned short* wp = W1f + ((size_t)kt << 13) + (w << 11) + (lz << 3);
        #pragma unroll
        for (int hf = 0; hf < 4; ++hf)
            wf[hf] = *(const bf16x8*)(wp + (hf << 9));
    };
    auto compute = [&](int b, const bf16x8* wf) {
        bf16x8 xf[4];
        #pragma unroll
        for (int nfn = 0; nfn < 4; ++nfn)
            xf[nfn] = *(const bf16x8*)&BX[((((b << 2) + nfn) << 6) + lz) << 3];
        #pragma unroll
        for (int nfn = 0; nfn < 4; ++nfn)
            #pragma unroll
            for (int hf = 0; hf < 4; ++hf)
                acc[nfn][hf] = __builtin_amdgcn_mfma_f32_16x16x32_bf16(
                    wf[hf], xf[nfn], acc[nfn][hf], 0, 0, 0);
    };

    bf16x8 wfc[4], wfn[4];
    float4 sAa, sAb, sBa, sBb;
    {
        float4 xa = xp[q4a], xb = xp[q4b];
        wload(0, wfc);
        xwrite(0, xa, xb);
        sAa = xp[8 + q4a]; sAb = xp[8 + q4b];
    }
    __syncthreads();

    #pragma unroll 1
    for (int kt = 0; kt < 16; kt += 2) {
        if (kt + 2 < 16) { sBa = xp[((kt + 2) << 3) + q4a]; sBb = xp[((kt + 2) << 3) + q4b]; }
        wload(kt + 1, wfn);
        compute(0, wfc);
        xwrite(1, sAa, sAb);
        __syncthreads();
        if (kt + 3 < 16) { sAa = xp[((kt + 3) << 3) + q4a]; sAb = xp[((kt + 3) << 3) + q4b]; }
        if (kt + 2 < 16) wload(kt + 2, wfc);
        compute(1, wfn);
        if (kt + 2 < 16) xwrite(0, sBa, sBb);
        __syncthreads();
    }

    {
        float4 b1q[4];
        #pragma unroll
        for (int hf = 0; hf < 4; ++hf)
            b1q[hf] = *(const float4*)(b1 + (w << 6) + (hf << 4) + ((lz >> 4) << 2));
        #pragma unroll
        for (int nfn = 0; nfn < 4; ++nfn) {
            #pragma unroll
            for (int cl = 0; cl < 2; ++cl) {
                f32x4 a0 = acc[nfn][2 * cl], a1 = acc[nfn][2 * cl + 1];
                float4 c0 = b1q[2 * cl], c1 = b1q[2 * cl + 1];
                uint4 pv;
                pv.x = pk2(fmaxf(a0.x + c0.x, 0.f), fmaxf(a0.y + c0.y, 0.f));
                pv.y = pk2(fmaxf(a0.z + c0.z, 0.f), fmaxf(a0.w + c0.w, 0.f));
                pv.z = pk2(fmaxf(a1.x + c1.x, 0.f), fmaxf(a1.y + c1.y, 0.f));
                pv.w = pk2(fmaxf(a1.z + c1.z, 0.f), fmaxf(a1.w + c1.w, 0.f));
                *(uint4*)&B2L[((((nfn << 3) + (w << 1) + cl) << 6) + lz) << 3] = pv;
            }
        }
    }
    __syncthreads();

    f32x4 acc2[4];
    #pragma unroll
    for (int nf2 = 0; nf2 < 4; ++nf2) acc2[nf2] = (f32x4)(0.f);

    #pragma unroll
    for (int c = 0; c < 8; ++c) {
        bf16x8 hfrag = *(const bf16x8*)&B2L[((((w << 3) + c) << 6) + lz) << 3];
        #pragma unroll
        for (int nf2 = 0; nf2 < 4; ++nf2) {
            bf16x8 wfrag = *(const bf16x8*)(W2f + (((c << 2) + nf2) << 9) + (lz << 3));
            acc2[nf2] = __builtin_amdgcn_mfma_f32_16x16x32_bf16(
                wfrag, hfrag, acc2[nf2], 0, 0, 0);
        }
    }

    {
        const int mloc = (w << 4) + (lz & 15);
        #pragma unroll
        for (int nf2 = 0; nf2 < 4; ++nf2) {
            float4 bq = *(const float4*)(b2 + (nf2 << 4) + ((lz >> 4) << 2));
            float4 hv;
            hv.x = acc2[nf2].x + bq.x; hv.y = acc2[nf2].y + bq.y;
            hv.z = acc2[nf2].z + bq.z; hv.w = acc2[nf2].w + bq.w;
            *(float4*)&H0L[mloc * 68 + (nf2 << 4) + ((lz >> 4) << 2)] = hv;
        }
    }
    __syncthreads();

    {
        const int m = t >> 2, q = t & 3;
        const int g = row0 + m;
        if (g < n) {
            unsigned* hp = hpack + (size_t)g * 32 + (q << 3);
            #pragma unroll
            for (int i = 0; i < 16; i += 4) {
                float4 hv = *(const float4*)&H0L[m * 68 + (q << 4) + i];
                uint2 pv;
                pv.x = pk2(hv.x, hv.y);
                pv.y = pk2(hv.z, hv.w);
                *(uint2*)(hp + (i >> 1)) = pv;
            }
        }
    }
}

// ---------------------------------------------------------------------------
// CSR build via single-digit bucket sort (bucket = row >> 8).
// Unified 16B brec records — exact R9/R10-verified version.
// ---------------------------------------------------------------------------
__global__ __launch_bounds__(256) void kA_hist(
    const int* __restrict__ erow, int* __restrict__ bcnt, int e, int nbk)
{
    __shared__ int lh[512];
    const int t = threadIdx.x;
    for (int b = t; b < 512; b += 256) lh[b] = 0;
    __syncthreads();
    for (int i = blockIdx.x * 256 + t; i < e; i += gridDim.x * 256)
        atomicAdd(&lh[erow[i] >> 8], 1);
    __syncthreads();
    for (int b = t; b < nbk; b += 256)
        if (lh[b]) atomicAdd(&bcnt[b], lh[b]);
}

__global__ __launch_bounds__(512) void kB_scan(
    const int* __restrict__ bcnt, int* __restrict__ bbase,
    int* __restrict__ gcur, int e, int nbk)
{
    __shared__ int sm[512];
    const int tid = threadIdx.x;
    const int v = (tid < nbk) ? bcnt[tid] : 0;
    sm[tid] = v;
    __syncthreads();
    for (int off = 1; off < 512; off <<= 1) {
        int tv = (tid >= off) ? sm[tid - off] : 0;
        __syncthreads();
        sm[tid] += tv;
        __syncthreads();
    }
    if (tid < nbk) {
        const int base = sm[tid] - v;
        bbase[tid] = base;
        gcur[tid * 16] = base;        // 64B-padded cursor
    }
    if (tid == 0) bbase[nbk] = e;
}

__global__ __launch_bounds__(256) void k_bapp(
    const int* __restrict__ erow, const int* __restrict__ ecol,
    const float* __restrict__ ev, int* __restrict__ gcur,
    uint4* __restrict__ brec, int e, int nbk)
{
    __shared__ int lh[512];
    __shared__ int lbase[512];
    const int t = threadIdx.x;
    const int c0 = blockIdx.x * 4096;
    for (int b = t; b < 512; b += 256) lh[b] = 0;
    __syncthreads();
    int rr[16];
    #pragma unroll
    for (int j = 0; j < 16; ++j) {
        const int i = c0 + j * 256 + t;
        rr[j] = (i < e) ? erow[i] : -1;
        if (rr[j] >= 0) atomicAdd(&lh[rr[j] >> 8], 1);
    }
    __syncthreads();
    for (int b = t; b < nbk; b += 256) {
        const int c = lh[b];
        lbase[b] = c ? atomicAdd(&gcur[b * 16], c) : 0;
        lh[b] = 0;
    }
    __syncthreads();
    #pragma unroll
    for (int j = 0; j < 16; ++j) {
        const int i = c0 + j * 256 + t;
        if (rr[j] >= 0) {
            const int b  = rr[j] >> 8;
            const int rk = atomicAdd(&lh[b], 1);
            uint4 rec;
            rec.x = (unsigned)rr[j];
            rec.y = (unsigned)ecol[i];
            rec.z = __float_as_uint(ev[i]);
            rec.w = 0;
            brec[lbase[b] + rk] = rec;
        }
    }
}

__global__ __launch_bounds__(256) void k_brow(
    const uint4* __restrict__ brec, const int* __restrict__ bbase,
    int* __restrict__ rp, int n, int e)
{
    __shared__ int rc[256];
    __shared__ int sc[256];
    const int b = blockIdx.x, t = threadIdx.x;
    const int lo = bbase[b], hi = bbase[b + 1];
    rc[t] = 0;
    __syncthreads();
    for (int i = lo + t; i < hi; i += 256) {
        const unsigned r = ((const unsigned*)brec)[(size_t)i * 4];
        atomicAdd(&rc[r & 255], 1);
    }
    __syncthreads();
    const int v = rc[t];
    sc[t] = v;
    __syncthreads();
    for (int off = 1; off < 256; off <<= 1) {
        int tv = (t >= off) ? sc[t - off] : 0;
        __syncthreads();
        sc[t] += tv;
        __syncthreads();
    }
    const int row = (b << 8) + t;
    if (row < n) rp[row] = lo + sc[t] - v;
    if (b == 0 && t == 0) rp[n] = e;
}

__global__ __launch_bounds__(256) void k_bwrite(
    const uint4* __restrict__ brec, const int* __restrict__ bbase,
    const int* __restrict__ rp, unsigned long long* __restrict__ cpack)
{
    __shared__ int rc[256];
    const int b = blockIdx.x, t = threadIdx.x;
    const int lo = bbase[b], hi = bbase[b + 1];
    rc[t] = 0;
    __syncthreads();
    for (int i = lo + t; i < hi; i += 256) {
        const uint4 rec = brec[i];
        const int rk = atomicAdd(&rc[rec.x & 255], 1);
        cpack[rp[rec.x] + rk] = ((unsigned long long)rec.z << 32) | rec.y;
    }
}

// ---------------------------------------------------------------------------
// One propagation hop (pull, CSR, bf16-packed h). 8-deep gather pipeline.
// (verified R10)
// ---------------------------------------------------------------------------
__device__ __forceinline__ void hop_accum(
    const unsigned* __restrict__ h_in, const int* __restrict__ row_ptr,
    const unsigned long long* __restrict__ cpack, int node, int sl,
    float& a0, float& a1)
{
    const int start = row_ptr[node];
    const int end   = row_ptr[node + 1];
    for (int base = start; base < end; base += 32) {
        const int idx = base + sl;
        unsigned long long pc = (idx < end) ? cpack[idx] : 0ULL;
        int   c = (int)(unsigned)pc;
        float v = __uint_as_float((unsigned)(pc >> 32));
        const int cnt = min(32, end - base);
        int e = 0;
        for (; e + 8 <= cnt; e += 8) {
            int cc[8]; float vv[8]; unsigned gg[8];
            #pragma unroll
            for (int j = 0; j < 8; ++j) {
                cc[j] = __shfl(c, e + j, 32);
                vv[j] = __shfl(v, e + j, 32);
            }
            #pragma unroll
            for (int j = 0; j < 8; ++j)
                gg[j] = h_in[(size_t)cc[j] * 32 + sl];
            #pragma unroll
            for (int j = 0; j < 8; ++j) {
                a0 = fmaf(vv[j], bflo(gg[j]), a0);
                a1 = fmaf(vv[j], bfhi(gg[j]), a1);
            }
        }
        for (; e + 4 <= cnt; e += 4) {
            int cc[4]; float vv[4]; unsigned gg[4];
            #pragma unroll
            for (int j = 0; j < 4; ++j) {
                cc[j] = __shfl(c, e + j, 32);
                vv[j] = __shfl(v, e + j, 32);
            }
            #pragma unroll
            for (int j = 0; j < 4; ++j)
                gg[j] = h_in[(size_t)cc[j] * 32 + sl];
            #pragma unroll
            for (int j = 0; j < 4; ++j) {
                a0 = fmaf(vv[j], bflo(gg[j]), a0);
                a1 = fmaf(vv[j], bfhi(gg[j]), a1);
            }
        }
        for (; e < cnt; ++e) {
            int   cc = __shfl(c, e, 32);
            float vv = __shfl(v, e, 32);
            unsigned g = h_in[(size_t)cc * 32 + sl];
            a0 = fmaf(vv, bflo(g), a0); a1 = fmaf(vv, bfhi(g), a1);
        }
    }
}

__global__ __launch_bounds__(256) void hop_kernel(
    const unsigned* __restrict__ h_in, unsigned* __restrict__ h_out,
    const int* __restrict__ row_ptr, const unsigned long long* __restrict__ cpack,
    int n)
{
    const int t  = threadIdx.x;
    const int sl = t & 31;
    const int node = (blockIdx.x * 256 + t) >> 5;
    if (node >= n) return;
    float a0 = 0.f, a1 = 0.f;
    hop_accum(h_in, row_ptr, cpack, node, sl, a0, a1);
    h_out[(size_t)node * 32 + sl] = pk2(a0, a1);
}

// ---------------------------------------------------------------------------
// Last hop fused with the attention combine: computes h_10 in registers
// (never stored), then out[n] = sum_k sigmoid(h_k.s) h_k over k=0..10.
// k=10 term uses the same pk2-rounded values k_combine would have read.
// ---------------------------------------------------------------------------
__global__ __launch_bounds__(256) void hop_last(
    const unsigned* __restrict__ hbuf, const int* __restrict__ row_ptr,
    const unsigned long long* __restrict__ cpack, const float* __restrict__ s,
    float* __restrict__ out, int n)
{
    const int t  = threadIdx.x;
    const int sl = t & 31;
    const int node = (blockIdx.x * 256 + t) >> 5;
    if (node >= n) return;
    float a0 = 0.f, a1 = 0.f;
    hop_accum(hbuf + (size_t)(HOPS - 1) * n * 32, row_ptr, cpack, node, sl, a0, a1);
    const unsigned glast = pk2(a0, a1);       // identical rounding to stored path

    const float2 sv = ((const float2*)s)[sl];
    float o0 = 0.f, o1 = 0.f;
    #pragma unroll
    for (int k = 0; k < HOPS; ++k) {
        const unsigned g = hbuf[(size_t)k * n * 32 + (size_t)node * 32 + sl];
        const float lo = bflo(g), hi = bfhi(g);
        float tv = lo * sv.x + hi * sv.y;
        #pragma unroll
        for (int off = 16; off > 0; off >>= 1) tv += __shfl_xor(tv, off, 32);
        const float sg = 1.f / (1.f + expf(-tv));
        o0 = fmaf(sg, lo, o0);
        o1 = fmaf(sg, hi, o1);
    }
    {
        const float lo = bflo(glast), hi = bfhi(glast);
        float tv = lo * sv.x + hi * sv.y;
        #pragma unroll
        for (int off = 16; off > 0; off >>= 1) tv += __shfl_xor(tv, off, 32);
        const float sg = 1.f / (1.f + expf(-tv));
        o0 = fmaf(sg, lo, o0);
        o1 = fmaf(sg, hi, o1);
    }
    float2 ov; ov.x = o0; ov.y = o1;
    ((float2*)out)[(size_t)node * 32 + sl] = ov;
}

// ---------------------------------------------------------------------------
extern "C" void kernel_launch(void* const* d_in, const int* in_sizes, int n_in,
                              void* d_out, int out_size, void* d_ws, size_t ws_size,
                              hipStream_t stream)
{
    const float* x  = (const float*)d_in[0];
    const int*   er = (const int*)  d_in[1];
    const int*   ec = (const int*)  d_in[2];
    const float* ev = (const float*)d_in[3];
    const float* W1 = (const float*)d_in[4];
    const float* b1 = (const float*)d_in[5];
    const float* W2 = (const float*)d_in[6];
    const float* b2 = (const float*)d_in[7];
    const float* s  = (const float*)d_in[8];
    float* out = (float*)d_out;

    const int n = in_sizes[0] / NIN;   // 100000
    const int e = in_sizes[1];         // 1600000
    const int nbk = (n + 255) >> 8;    // 391 buckets

    char* w = (char*)d_ws;
    auto carve = [&](size_t bytes) { char* p = w; w += (bytes + 255) & ~(size_t)255; return p; };
    unsigned* hbuf   = (unsigned*)carve((size_t)HOPS * n * 32 * 4);        // 128 MB (h_0..h_9)
    int*      rp     = (int*)     carve(((size_t)n + 1) * 4);
    unsigned long long* cpack = (unsigned long long*)carve((size_t)e * 8); // 12.8 MB
    uint4*    brec   = (uint4*)   carve((size_t)e * 16);                   // 25.6 MB
    int*      bcnt   = (int*)     carve(512 * 4);
    int*      bbase  = (int*)     carve(513 * 4);
    int*      gcur   = (int*)     carve(512 * 16 * 4);
    unsigned short* W1f = (unsigned short*)carve((size_t)NHID * NIN * 2);
    unsigned short* W2f = (unsigned short*)carve((size_t)NOUT * NHID * 2);

    hipMemsetAsync(bcnt, 0, 512 * 4, stream);

    k_preconv<<<(NHID * NIN + 255) / 256, 256, 0, stream>>>(W1, W2, W1f, W2f);

    const int mgrid = (n + 63) / 64;
    mlp_kernel<<<mgrid, 256, 0, stream>>>(x, W1f, b1, W2f, b2, hbuf, n);

    kA_hist <<<256, 256, 0, stream>>>(er, bcnt, e, nbk);
    kB_scan <<<1, 512, 0, stream>>>(bcnt, bbase, gcur, e, nbk);
    k_bapp  <<<(e + 4095) / 4096, 256, 0, stream>>>(er, ec, ev, gcur, brec, e, nbk);
    k_brow  <<<nbk, 256, 0, stream>>>(brec, bbase, rp, n, e);
    k_bwrite<<<nbk, 256, 0, stream>>>(brec, bbase, rp, cpack);

    const int hgrid = ((size_t)n * 32 + 255) / 256;
    for (int hop = 0; hop < HOPS - 1; ++hop) {
        hop_kernel<<<hgrid, 256, 0, stream>>>(
            hbuf + (size_t)hop * n * 32, hbuf + (size_t)(hop + 1) * n * 32,
            rp, cpack, n);
    }
    hop_last<<<hgrid, 256, 0, stream>>>(hbuf, rp, cpack, s, out, n);
}